// Round 10
// baseline (5141.306 us; speedup 1.0000x reference)
//
#include <hip/hip_runtime.h>
#include <vector>
#include <cmath>
#include <cstdint>

// ---------------- static model tables (constexpr, device-usable) ----------------
constexpr int KLc[4]  = {256,192,128,64};     // k_max per l
constexpr int NMLc[4] = {8,6,4,2};            // radial basis per l
constexpr int SHBc[5] = {0,1,4,9,16};         // sh split bases
constexpr int RBBc[5] = {0,8,14,18,20};       // rb split bases
constexpr int FBc[5]  = {0,256,832,1472,1920};// feats flat base per l  (sum (2l+1)*K[l])
constexpr int NCMB = 34, CGTOT = 3436, FTOT = 1920;

struct Combos { int l1[NCMB], l2[NCMB], L[NCMB], cgoff[NCMB], kk[NCMB]; };
constexpr Combos make_combos(){
  Combos c{}; int n=0, cg=0;
  for(int a=0;a<=3;a++)for(int b=0;b<=3;b++){
    int lo=a>b?a-b:b-a, hi=(a+b<3)?(a+b):3;
    for(int L=lo;L<=hi;L++){
      c.l1[n]=a; c.l2[n]=b; c.L[n]=L; c.cgoff[n]=cg;
      int mx=a>b?a:b; if(L>mx) mx=L; c.kk[n]=KLc[mx];          // TP truncation (min of all three)
      cg+=(2*a+1)*(2*b+1)*(2*L+1); n++;
    }
  }
  return c;
}
constexpr Combos CB = make_combos();
static_assert(CB.cgoff[NCMB-1] + 7*7*7 == CGTOT, "cg size");

struct Grp { int cnt[4]; int list[4][12]; };
constexpr Grp make_Lg(){ Grp g{}; for(int i=0;i<NCMB;i++){ int L=CB.L[i]; g.list[L][g.cnt[L]++]=i; } return g; }
constexpr Grp LG = make_Lg();     // combos grouped by output L (for k_tp)

struct Rows { int sh[64], rb[64], off[64]; };
constexpr Rows make_rows(){ Rows r{}; int i=0;
  for(int l=0;l<4;l++)for(int m=0;m<2*l+1;m++)for(int n=0;n<NMLc[l];n++){
    r.sh[i]=SHBc[l]+m; r.rb[i]=RBBc[l]+n; r.off[i]=FBc[l]+m*KLc[l]+n*32; i++; }
  for(;i<64;i++){ r.sh[i]=0; r.rb[i]=0; r.off[i]=0; }
  return r; }
constexpr Rows RWS = make_rows();  // 60 (l,m,n) rows for invariant MP

// ---------------- k_eq tables: S-factorization, UNIFORM pair-loop layout ----------------
constexpr int NSL=425, NG=16, RPAD=149; // RPAD odd -> 2-way bank aliasing (free)
constexpr int DEPTH=6;                  // fg prefetch depth (rotating slots)
constexpr int NTILE=30;
constexpr int GSTR=1024;                // featsAg per-atom stride in dwords (4096 B)

constexpr int iabs_(int x){ return x<0?-x:x; }
__host__ __device__ constexpr bool sl_valid(int l1,int l2,int kt){ return l2<=3-kt && iabs_(l1-l2)<=3-kt; }

__host__ __device__ constexpr int rb_base(int kt,int l1,int l2){
  int base=0;
  for(int p=0;p<4;p++)for(int q=0;q<4;q++){
    if(p==l1 && q==l2) return base;
    if(sl_valid(p,q,kt)) base += (2*p+1)*(2*q+1);
  }
  return base;
}

struct EqTab {
  short       srow[NG][32];   // stage row within its dump phase (-1 = pad slot)
  signed char sph [NG][32];   // dump phase 0..4 (-1 = pad slot)
  int nr[NG];                 // tiles in group (1 or 2)
  short roff[NG][2];          // fg row offsets into feats (element units); [1]==[0] if nr==1
  int total;
};
constexpr EqTab make_eqtab(){
  EqTab T{};
  for(int g=0;g<NG;g++){
    for(int s=0;s<32;s++){ T.srow[g][s]=-1; T.sph[g][s]=-1; }
    T.nr[g]=0; T.roff[g][0]=0; T.roff[g][1]=0;
  }
  int tl2[NTILE]{}, tkt[NTILE]{}, tbb[NTILE]{}, tsz[NTILE]{}; int nt=0;
  for(int l2=0;l2<4;l2++)for(int kt=0;kt<4-l2;kt++)for(int b=0;b<2*l2+1;b++){
    int sz=0;
    for(int l1=0;l1<4;l1++) if(sl_valid(l1,l2,kt)) sz+=2*l1+1;
    tl2[nt]=l2; tkt[nt]=kt; tbb[nt]=b; tsz[nt]=sz; nt++;
  }
  bool used[NTILE]{}; int gload[NG]{}; int gcnt[NG]{}; int gt[NG][2]{};
  for(int it=0; it<nt; it++){
    int best=-1;
    for(int i=0;i<nt;i++) if(!used[i] && (best<0 || tsz[i]>tsz[best])) best=i;
    used[best]=true;
    int g=-1;
    for(int j=0;j<NG;j++) if(gcnt[j]<2 && (g<0 || gload[j]<gload[g])) g=j;
    gt[g][gcnt[g]]=best; gcnt[g]++; gload[g]+=tsz[best];
  }
  int total=0;
  for(int g=0;g<NG;g++){
    T.nr[g]=gcnt[g];
    for(int tk=0;tk<gcnt[g];tk++){
      const int ti=gt[g][tk];
      const int l2=tl2[ti], kt=tkt[ti], b=tbb[ti];
      T.roff[g][tk]=(short)(FBc[l2]+b*KLc[l2]+kt*64);
      for(int i=0;i<16;i++){
        const int l1=(i==0)?0:(i<4)?1:(i<9)?2:3;
        const int aa=i-SHBc[l1];
        if(!sl_valid(l1,l2,kt)) continue;
        const int s=tk*16+i;
        const int rbi=rb_base(kt,l1,l2)+aa*(2*l2+1)+b;
        int ph, sr;
        if(kt==0){ if(l1<=2){ ph=0; sr=rbi; } else { ph=1; sr=rbi-144; } }
        else { ph=kt+1; sr=rbi; }
        T.sph[g][s]=(signed char)ph; T.srow[g][s]=(short)sr;
        total++;
      }
    }
    if(gcnt[g]==1) T.roff[g][1]=T.roff[g][0];   // duplicate load, acc[16..31] never staged
  }
  T.total=total;
  return T;
}
constexpr EqTab ET = make_eqtab();
static_assert(ET.total==NSL, "slice count");
constexpr bool chk_srow(){ for(int g=0;g<NG;g++) for(int s=0;s<32;s++) if(ET.srow[g][s]>=RPAD) return false; return true; }
static_assert(chk_srow(), "stage rows fit RPAD");

// wave-uniform row offsets (flat arrays, runtime-indexed by group)
struct RoffA { int r0[NG]; int r1[NG]; };
constexpr RoffA make_roffa(){ RoffA R{}; for(int g=0;g<NG;g++){ R.r0[g]=ET.roff[g][0]; R.r1[g]=ET.roff[g][1]; } return R; }
constexpr RoffA RFA = make_roffa();

// contraction combo -> group assignment (greedy by cost n1*n2*nL)
struct CAsg { int cnt[NG]; unsigned char ci[NG][8]; };
constexpr CAsg make_casg(){
  CAsg C{}; bool used[NCMB]{}; int load[NG]{};
  for(int it=0; it<NCMB; it++){
    int best=-1, bc=-1;
    for(int i=0;i<NCMB;i++) if(!used[i]){
      int c=(2*CB.l1[i]+1)*(2*CB.l2[i]+1)*(2*CB.L[i]+1);
      if(c>bc){bc=c;best=i;}
    }
    used[best]=true;
    int g=0; for(int j=1;j<NG;j++) if(load[j]<load[g]) g=j;
    C.ci[g][C.cnt[g]++]=(unsigned char)best; load[g]+=bc;
  }
  return C;
}
constexpr CAsg CA = make_casg();
constexpr bool chk_ca(){ for(int g=0;g<NG;g++) if(CA.cnt[g]>8) return false; return true; }
static_assert(chk_ca(), "CA cap");

__host__ __device__ constexpr bool combo_in_phase(int ci,int ph){
  int l1=CB.l1[ci], l2=CB.l2[ci], L=CB.L[ci];
  if(ph==0) return l1<=2;
  if(ph==1) return l1==3;
  int kt=ph-1;
  return (l2<=3-kt) && (L<=3-kt);
}
__host__ __device__ constexpr int phase_kt(int ph){ return ph<=1?0:ph-1; }
__host__ __device__ constexpr int phase_rbadj(int ph){ return ph==1?144:0; }

// ---------------- host: numpy-legacy RandomState(0) CG generation ----------------
namespace nprng {
struct MT {
  uint32_t mt[624]; int mti; bool has_g; double g;
  void seed(uint32_t s){ for(int i=0;i<624;i++){ mt[i]=s; s=1812433253u*(s^(s>>30))+(uint32_t)i+1u; } mti=624; has_g=false; g=0.0; }
  uint32_t u32(){
    if(mti>=624){
      for(int i=0;i<624;i++){
        uint32_t y=(mt[i]&0x80000000u)|(mt[(i+1)%624]&0x7fffffffu);
        mt[i]=mt[(i+397)%624]^(y>>1)^((y&1u)?0x9908b0dfu:0u);
      }
      mti=0;
    }
    uint32_t y=mt[mti++];
    y^=y>>11; y^=(y<<7)&0x9d2c5680u; y^=(y<<15)&0xefc60000u; y^=y>>18;
    return y;
  }
  double dbl(){ uint32_t a=u32()>>5, b=u32()>>6; return (a*67108864.0+b)/9007199254740992.0; }
  double gauss(){
    if(has_g){ has_g=false; return g; }
    double f,x1,x2,r2;
    do{ x1=2.0*dbl()-1.0; x2=2.0*dbl()-1.0; r2=x1*x1+x2*x2; }while(r2>=1.0||r2==0.0);
    f=sqrt(-2.0*log(r2)/r2);
    g=f*x1; has_g=true; return f*x2;
  }
};
}
static std::vector<float> build_cg(){
  nprng::MT r; r.seed(0);
  std::vector<float> v; v.reserve(CGTOT);
  for(int l1=0;l1<=3;l1++)for(int l2=0;l2<=3;l2++){
    int lo = l1>l2? l1-l2 : l2-l1;
    int hi = (l1+l2<3)? (l1+l2) : 3;
    for(int L=lo;L<=hi;L++){
      int n=(2*l1+1)*(2*l2+1)*(2*L+1);
      for(int i=0;i<n;i++) v.push_back((float)(r.gauss()*0.2));
    }
  }
  return v;
}

// ---------------- small setup kernels ----------------
__global__ __launch_bounds__(256) void k_cemb(const float* __restrict__ emb_table,
    const int* __restrict__ species, float* __restrict__ cemb, int* __restrict__ counts, int N){
  int i = blockIdx.x*256 + threadIdx.x;
  if(i < N) counts[i] = 0;
  if(i < N*32){ int n = i>>5, c = i&31; cemb[i] = emb_table[species[n]*32 + c]; }
}

__global__ __launch_bounds__(256) void k_hist(const int* __restrict__ centers, int* counts, int P){
  int i = blockIdx.x*256 + threadIdx.x;
  if(i < P) atomicAdd(&counts[centers[i]], 1);
}

__global__ __launch_bounds__(256) void k_scan(const int* __restrict__ counts,
    int* __restrict__ offsets, int* __restrict__ cursor, int N){
  __shared__ int part[256];
  const int t = threadIdx.x;
  const int CH = (N + 255)/256;
  const int lo = t*CH;
  int hi = (t+1)*CH; if(hi > N) hi = N;
  int s = 0;
  for(int i=lo;i<hi;i++) s += counts[i];
  part[t] = s; __syncthreads();
  const int own = s;
  for(int d=1; d<256; d<<=1){
    int v = (t>=d)? part[t-d] : 0;
    __syncthreads();
    part[t] += v;
    __syncthreads();
  }
  int run = part[t] - own;
  for(int i=lo;i<hi;i++){ offsets[i]=run; cursor[i]=run; run += counts[i]; }
  if(t==255) offsets[N] = part[255];
}

__global__ __launch_bounds__(256) void k_scatter(const int* __restrict__ centers,
    int* cursor, int* __restrict__ perm, int P){
  int i = blockIdx.x*256 + threadIdx.x;
  if(i < P){ int c = centers[i]; int pos = atomicAdd(&cursor[c], 1); perm[pos] = i; }
}

// ---------------- pair-order precompute: PACKED FP16 edge components + neighbor ids ----
// edge_ph[pos*16+i] = fp16( sh[p*16+i] * 0.1 * sum(rb[p, l-range(i)]) )
__global__ __launch_bounds__(256) void k_permute(const float* __restrict__ sh,
    const float* __restrict__ rb, const int* __restrict__ nbrs, const int* __restrict__ perm,
    unsigned short* __restrict__ edge_ph, int* __restrict__ nbrp, int P){
  int u = blockIdx.x*256 + threadIdx.x;
  int pos = u>>4, i = u&15;
  if(pos >= P) return;
  int p = perm[pos];
  if(i==0) nbrp[pos] = nbrs[p];
  int l = (i==0)?0:(i<4)?1:(i<9)?2:3;
  float s=0.f;
  for(int n=RBBc[l]; n<RBBc[l+1]; n++) s += rb[p*20+n];
  float e = sh[p*16+i]*0.1f*s;   // sh * NU_SCALING * rb.sum
  _Float16 h = (_Float16)e;
  edge_ph[(size_t)pos*16+i] = *(unsigned short*)&h;
}

// ---------------- grouped fp16 gather table, neighbor-embedding BAKED IN ------------
// featsAg[n][g][r][i] (stride GSTR dwords = 4096 B/atom) = fp16(featsA[n][roff(g,r)+i] * cemb[n][i&31])
__global__ __launch_bounds__(256) void k_halfg(const float* __restrict__ src,
    const float* __restrict__ cemb, unsigned int* __restrict__ dst, int N){
  int u = blockIdx.x*256 + threadIdx.x;
  if(u >= N*GSTR) return;
  int n = u >> 10, o = u & 1023;          // o: dword within atom record
  int g = o >> 6, i = o & 63;             // g: wave group, i: lane
  float c = cemb[n*32 + (i&31)];
  float v0 = src[(size_t)n*FTOT + RFA.r0[g] + i] * c;
  float v1 = src[(size_t)n*FTOT + RFA.r1[g] + i] * c;
  _Float16 h0 = (_Float16)v0, h1 = (_Float16)v1;
  unsigned int lo = *(unsigned short*)&h0, hi = *(unsigned short*)&h1;
  dst[u] = lo | (hi<<16);
}

// ---------------- invariant MP (batched pairs, 3 barriers / 8 pairs) ----------------
__global__ __launch_bounds__(256) void k_inv(const float* __restrict__ sh, const float* __restrict__ rb,
    const float* __restrict__ cemb, const int* __restrict__ nbrs, const int* __restrict__ offsets,
    const int* __restrict__ perm, float* __restrict__ feats){
  const int a = blockIdx.x, t = threadIdx.x;
  __shared__ float sh_s[8][16], rb_s[8][20], emb_s[8][32], shrb_s[8][60];
  const int c = t & 31, rg = t >> 5;
  float acc[8];
  #pragma unroll
  for(int j=0;j<8;j++) acc[j] = 0.f;
  const int beg = offsets[a], cnt = offsets[a+1]-beg;
  for(int jb=0; jb<cnt; jb+=8){
    __syncthreads();
    for(int u=t; u<8*36; u+=256){
      int j=u/36, i=u-36*j;
      if(jb+j<cnt){
        int p=perm[beg+jb+j];
        if(i<16) sh_s[j][i]=sh[p*16+i]*0.1f;      // NU_SCALING
        else     rb_s[j][i-16]=rb[p*20+i-16];
      }
    }
    for(int u=t; u<8*32; u+=256){
      int j=u>>5, i=u&31;
      if(jb+j<cnt){ int nb=nbrs[perm[beg+jb+j]]; emb_s[j][i]=cemb[(size_t)nb*32+i]; }
    }
    __syncthreads();
    for(int u=t; u<8*60; u+=256){
      int j=u/60, r=u-60*j;
      if(jb+j<cnt) shrb_s[j][r] = sh_s[j][RWS.sh[r]] * rb_s[j][RWS.rb[r]];
    }
    __syncthreads();
    const int jm = (cnt-jb<8)?(cnt-jb):8;
    for(int j=0;j<jm;j++){
      const float e = emb_s[j][c];
      #pragma unroll
      for(int q=0;q<8;q++){ int r=rg+8*q; if(r<60) acc[q]=fmaf(shrb_s[j][r], e, acc[q]); }
    }
  }
  #pragma unroll
  for(int q=0;q<8;q++){
    int r = rg + 8*q;
    if(r < 60) feats[(size_t)a*FTOT + RWS.off[r] + c] = 0.1f * acc[q];  // MP_SCALING
  }
}

// ---------------- CG iterate (in-place): feats = feats + 0.1 * TP(feats, feats) ----------------
__device__ __forceinline__ float cg_u(const float* __restrict__ cg, int idx){
  return cg[__builtin_amdgcn_readfirstlane(idx)];
}
__global__ __launch_bounds__(256) void k_tp(float* __restrict__ feats, const float* __restrict__ cg){
  const int a = blockIdx.x, t = threadIdx.x;
  __shared__ float f_s[FTOT];
  float* fa = feats + (size_t)a*FTOT;
  for(int i=t;i<FTOT;i+=256)  f_s[i]  = fa[i];
  __syncthreads();
  #pragma unroll
  for(int L=0; L<4; L++){
    const int KLL = KLc[L], nL = 2*L+1;
    const int nel = nL*KLL;
    for(int e=t; e<nel; e+=256){
      const int M = e / KLL, k = e - M*KLL;
      float acc = 0.f;
      #pragma unroll
      for(int gi=0; gi<LG.cnt[L]; gi++){
        const int ci = LG.list[L][gi];
        const int l1 = CB.l1[ci], l2 = CB.l2[ci];
        if(k < CB.kk[ci]){
          const int n2 = 2*l2+1;
          #pragma unroll
          for(int aa=0; aa<2*l1+1; aa++){
            const float Av = f_s[FBc[l1] + aa*KLc[l1] + k];
            #pragma unroll
            for(int b=0; b<n2; b++)
              acc += cg_u(cg, CB.cgoff[ci] + (aa*n2+b)*nL + M) * (Av * f_s[FBc[l2] + b*KLc[l2] + k]);
          }
        }
      }
      fa[FBc[L] + M*KLL + k] = f_s[FBc[L] + M*KLL + k] + 0.1f*acc;   // NU_SCALING residual
    }
  }
}

// ---------------- equivariant MP v13: register-resident fp16 edges, memory-free consume ----------------
template<int G,int PH,int U>
__device__ __forceinline__ void contract_combos(const float* __restrict__ stageT,
    float* __restrict__ out_s, const float* __restrict__ cg, int lane){
  if constexpr (U < CA.cnt[G]) {
    constexpr int ci = CA.ci[G][U];
    if constexpr (combo_in_phase(ci,PH)) {
      constexpr int l1=CB.l1[ci], l2=CB.l2[ci], L=CB.L[ci];
      constexpr int n1=2*l1+1, n2=2*l2+1, nL=2*L+1;
      constexpr int kt=phase_kt(PH);
      constexpr int rbase = rb_base(kt,l1,l2) - phase_rbadj(PH);
      float oa[nL];
      #pragma unroll
      for(int M=0;M<nL;M++) oa[M]=0.f;
      #pragma unroll
      for(int aa=0;aa<n1;aa++){
        #pragma unroll
        for(int b=0;b<n2;b++){
          const float sv = stageT[lane*RPAD + rbase + aa*n2 + b];
          #pragma unroll
          for(int M=0;M<nL;M++)
            oa[M] = fmaf(cg[CB.cgoff[ci] + (aa*n2+b)*nL + M], sv, oa[M]);  // uniform idx -> s_load
        }
      }
      #pragma unroll
      for(int M=0;M<nL;M++)
        atomicAdd(&out_s[FBc[L] + M*KLc[L] + kt*64 + lane], oa[M]);
    }
    contract_combos<G,PH,U+1>(stageT,out_s,cg,lane);
  }
}

template<int G,int PH>
__device__ __forceinline__ void eq_phase(const float* acc, float* stageT, float* out_s,
    const float* __restrict__ cg, int lane){
  __syncthreads();                       // protect previous phase's stage reads
  #pragma unroll
  for(int s=0;s<32;s++){
    if(ET.sph[G][s]==PH) stageT[lane*RPAD + ET.srow[G][s]] = acc[s];  // constexpr-folded
  }
  __syncthreads();
  contract_combos<G,PH,0>(stageT,out_s,cg,lane);
}

template<int G>
__device__ __forceinline__ void eq_phases(const float* acc, float* stageT, float* out_s,
    const float* __restrict__ cg, int lane){
  eq_phase<G,0>(acc,stageT,out_s,cg,lane);
  eq_phase<G,1>(acc,stageT,out_s,cg,lane);
  eq_phase<G,2>(acc,stageT,out_s,cg,lane);
  eq_phase<G,3>(acc,stageT,out_s,cg,lane);
  eq_phase<G,4>(acc,stageT,out_s,cg,lane);
}

// consume 4 packed-fp16 edge dwords (one uint4 batch register) for pair q
__device__ __forceinline__ void eq_consume4(float* accA, float* accB,
    const unsigned* e, int q, float f0, float f1){
  #pragma unroll
  for(int r=0;r<4;r++){
    const unsigned d = (unsigned)__builtin_amdgcn_readlane((int)e[r], q);  // -> SGPR
    union { unsigned short s; _Float16 h; } u0, u1;
    u0.s = (unsigned short)(d & 0xffffu);
    u1.s = (unsigned short)(d >> 16);
    const float elo = (float)u0.h, ehi = (float)u1.h;   // v_cvt_f32_f16
    accA[2*r]   = fmaf(elo, f0, accA[2*r]);
    accB[2*r]   = fmaf(elo, f1, accB[2*r]);
    accA[2*r+1] = fmaf(ehi, f0, accA[2*r+1]);
    accB[2*r+1] = fmaf(ehi, f1, accB[2*r+1]);
  }
}

__global__ __launch_bounds__(1024,8) void k_eq2(const unsigned short* __restrict__ edge_ph,
    const int* __restrict__ nbrp, const int* __restrict__ offsets,
    const unsigned int* __restrict__ featsAg,
    float* __restrict__ featsB, const float* __restrict__ cg){
  __shared__ float stageT[64*RPAD];   // 38144 B, odd lane stride -> conflict-free
  __shared__ float out_s[FTOT];       // 7680 B
  const int a = blockIdx.x, t = threadIdx.x, lane = t&63, g = t>>6;

  float acc[32];
  #pragma unroll
  for(int s=0;s<32;s++) acc[s]=0.f;
  for(int i=t;i<FTOT;i+=1024) out_s[i]=0.f;
  const int beg = offsets[a], cnt = offsets[a+1]-beg;

  for(int jb=0; jb<cnt; jb+=64){
    const int jm = (cnt-jb<64)?(cnt-jb):64;
    // batch state: lane l holds pair (jb+l)'s nb + 16 packed-fp16 edges (8 dwords)
    int pofs = jb + lane; if(pofs > cnt-1) pofs = cnt-1;
    const int nbv = nbrp[beg + pofs];
    const uint4 eA = *(const uint4*)(edge_ph + (size_t)(beg+pofs)*16);
    const uint4 eB = *(const uint4*)(edge_ph + (size_t)(beg+pofs)*16 + 8);

    // fg prefetch slots (vmcnt-pipelined; addresses via readlane -> SGPR base + t)
    unsigned int fgS[DEPTH];
    #pragma unroll
    for(int s=0;s<DEPTH;s++){
      int qq = (s<jm)? s : jm-1;
      unsigned nb = (unsigned)__builtin_amdgcn_readlane(nbv, qq);
      fgS[s] = featsAg[(size_t)nb*GSTR + t];
    }
    for(int j=0;j<jm;j+=DEPTH){
      #pragma unroll
      for(int s=0;s<DEPTH;s++){
        const int q = j+s;
        if(q < jm){
          const unsigned int v = fgS[s];        // counted vmcnt wait (compiler)
          const int qn = q + DEPTH;
          if(qn < jm){                           // refill slot with pair DEPTH ahead
            unsigned nb = (unsigned)__builtin_amdgcn_readlane(nbv, qn);
            fgS[s] = featsAg[(size_t)nb*GSTR + t];
          }
          union { unsigned int u; _Float16 h[2]; } cv; cv.u = v;
          const float f0 = (float)cv.h[0], f1 = (float)cv.h[1];
          eq_consume4(acc,    acc+16, (const unsigned*)&eA, q, f0, f1);
          eq_consume4(acc+8,  acc+24, (const unsigned*)&eB, q, f0, f1);
        }
      }
    }
  }

  // once-per-block contract phases (each begins with __syncthreads -> covers out_s init)
  switch(g){
    case 0:  eq_phases<0 >(acc,stageT,out_s,cg,lane); break;
    case 1:  eq_phases<1 >(acc,stageT,out_s,cg,lane); break;
    case 2:  eq_phases<2 >(acc,stageT,out_s,cg,lane); break;
    case 3:  eq_phases<3 >(acc,stageT,out_s,cg,lane); break;
    case 4:  eq_phases<4 >(acc,stageT,out_s,cg,lane); break;
    case 5:  eq_phases<5 >(acc,stageT,out_s,cg,lane); break;
    case 6:  eq_phases<6 >(acc,stageT,out_s,cg,lane); break;
    case 7:  eq_phases<7 >(acc,stageT,out_s,cg,lane); break;
    case 8:  eq_phases<8 >(acc,stageT,out_s,cg,lane); break;
    case 9:  eq_phases<9 >(acc,stageT,out_s,cg,lane); break;
    case 10: eq_phases<10>(acc,stageT,out_s,cg,lane); break;
    case 11: eq_phases<11>(acc,stageT,out_s,cg,lane); break;
    case 12: eq_phases<12>(acc,stageT,out_s,cg,lane); break;
    case 13: eq_phases<13>(acc,stageT,out_s,cg,lane); break;
    case 14: eq_phases<14>(acc,stageT,out_s,cg,lane); break;
    default: eq_phases<15>(acc,stageT,out_s,cg,lane); break;
  }
  __syncthreads();
  float* ob = featsB + (size_t)a*FTOT;
  for(int i=t;i<FTOT;i+=1024) ob[i] = 0.1f*out_s[i];       // MP_SCALING
}

// ---------------- DIAGNOSTIC: identical kernel, fg-gather ablated (opaque const) ---------
// Localizes the residual stall: if this is much faster than k_eq2, the gather is the wall.
__global__ __launch_bounds__(1024,8) void k_eq2_nofg(const unsigned short* __restrict__ edge_ph,
    const int* __restrict__ offsets, float* __restrict__ dummyB, const float* __restrict__ cg){
  __shared__ float stageT[64*RPAD];
  __shared__ float out_s[FTOT];
  const int a = blockIdx.x, t = threadIdx.x, lane = t&63, g = t>>6;
  float acc[32];
  #pragma unroll
  for(int s=0;s<32;s++) acc[s]=0.f;
  for(int i=t;i<FTOT;i+=1024) out_s[i]=0.f;
  const int beg = offsets[a], cnt = offsets[a+1]-beg;
  for(int jb=0; jb<cnt; jb+=64){
    const int jm = (cnt-jb<64)?(cnt-jb):64;
    int pofs = jb + lane; if(pofs > cnt-1) pofs = cnt-1;
    const uint4 eA = *(const uint4*)(edge_ph + (size_t)(beg+pofs)*16);
    const uint4 eB = *(const uint4*)(edge_ph + (size_t)(beg+pofs)*16 + 8);
    for(int j=0;j<jm;j+=DEPTH){
      #pragma unroll
      for(int s=0;s<DEPTH;s++){
        const int q = j+s;
        if(q < jm){
          unsigned int v;                                   // opaque: no load, not foldable
          asm volatile("v_mov_b32 %0, 0x3c003c00" : "=v"(v));
          union { unsigned int u; _Float16 h[2]; } cv; cv.u = v;
          const float f0 = (float)cv.h[0], f1 = (float)cv.h[1];
          eq_consume4(acc,    acc+16, (const unsigned*)&eA, q, f0, f1);
          eq_consume4(acc+8,  acc+24, (const unsigned*)&eB, q, f0, f1);
        }
      }
    }
  }
  switch(g){
    case 0:  eq_phases<0 >(acc,stageT,out_s,cg,lane); break;
    case 1:  eq_phases<1 >(acc,stageT,out_s,cg,lane); break;
    case 2:  eq_phases<2 >(acc,stageT,out_s,cg,lane); break;
    case 3:  eq_phases<3 >(acc,stageT,out_s,cg,lane); break;
    case 4:  eq_phases<4 >(acc,stageT,out_s,cg,lane); break;
    case 5:  eq_phases<5 >(acc,stageT,out_s,cg,lane); break;
    case 6:  eq_phases<6 >(acc,stageT,out_s,cg,lane); break;
    case 7:  eq_phases<7 >(acc,stageT,out_s,cg,lane); break;
    case 8:  eq_phases<8 >(acc,stageT,out_s,cg,lane); break;
    case 9:  eq_phases<9 >(acc,stageT,out_s,cg,lane); break;
    case 10: eq_phases<10>(acc,stageT,out_s,cg,lane); break;
    case 11: eq_phases<11>(acc,stageT,out_s,cg,lane); break;
    case 12: eq_phases<12>(acc,stageT,out_s,cg,lane); break;
    case 13: eq_phases<13>(acc,stageT,out_s,cg,lane); break;
    case 14: eq_phases<14>(acc,stageT,out_s,cg,lane); break;
    default: eq_phases<15>(acc,stageT,out_s,cg,lane); break;
  }
  __syncthreads();
  float* ob = dummyB + (size_t)a*FTOT;
  for(int i=t;i<FTOT;i+=1024) ob[i] = 0.1f*out_s[i];
}

// ---------------- energy readout ----------------
__global__ __launch_bounds__(256) void k_energy(const float* __restrict__ feats,
    const float* __restrict__ cemb, const float* __restrict__ wE, const float* __restrict__ bE,
    float* __restrict__ out, int N){
  const int wid = threadIdx.x >> 6, lane = threadIdx.x & 63;
  const int a = blockIdx.x*4 + wid;
  if(a >= N) return;
  const float e = cemb[(size_t)a*32 + (lane & 31)];
  float s = 0.f;
  for(int k=lane; k<256; k+=64) s += feats[(size_t)a*FTOT + k] * e * wE[k];
  #pragma unroll
  for(int off=32; off; off>>=1) s += __shfl_down(s, off, 64);
  if(lane == 0) out[a] = s + bE[0];
}

// ---------------- launcher ----------------
extern "C" void kernel_launch(void* const* d_in, const int* in_sizes, int n_in,
                              void* d_out, int out_size, void* d_ws, size_t ws_size,
                              hipStream_t stream){
  const float* sh        = (const float*)d_in[0];
  const float* rb        = (const float*)d_in[1];
  const float* emb_table = (const float*)d_in[2];
  const float* wE        = (const float*)d_in[3];
  const float* bE        = (const float*)d_in[4];
  const int*   species   = (const int*)d_in[5];
  const int*   centers   = (const int*)d_in[6];
  const int*   nbrs      = (const int*)d_in[7];
  const int N = in_sizes[5];
  const int P = in_sizes[6];

  char* ws = (char*)d_ws; size_t off = 0;
  auto carve = [&](size_t bytes)->void*{
    void* p = ws + off; off = (off + bytes + 255) & ~(size_t)255; return p;
  };
  float* cg_d    = (float*)carve((size_t)CGTOT*4);
  float* cemb    = (float*)carve((size_t)N*32*4);
  int*   counts  = (int*)  carve((size_t)N*4);
  int*   offsets = (int*)  carve((size_t)(N+1)*4);
  int*   cursor  = (int*)  carve((size_t)N*4);
  int*   perm    = (int*)  carve((size_t)P*4);
  unsigned short* edge_ph = (unsigned short*)carve((size_t)P*16*2);
  int*   nbrp    = (int*)  carve((size_t)(P+64)*4);
  float* featsA  = (float*)carve((size_t)N*FTOT*4);   // reused as diagnostic dump after k_halfg
  float* featsB  = (float*)carve((size_t)N*FTOT*4);
  unsigned int* featsAg = (unsigned int*)carve((size_t)N*GSTR*4);
  (void)ws_size; (void)n_in; (void)out_size;

  static const std::vector<float> cg_host = build_cg();  // deterministic; host-side cache only
  hipMemcpyAsync(cg_d, cg_host.data(), (size_t)CGTOT*4, hipMemcpyHostToDevice, stream);

  k_cemb   <<<(N*32 + 255)/256, 256, 0, stream>>>(emb_table, species, cemb, counts, N);
  k_hist   <<<(P + 255)/256,    256, 0, stream>>>(centers, counts, P);
  k_scan   <<<1,                256, 0, stream>>>(counts, offsets, cursor, N);
  k_scatter<<<(P + 255)/256,    256, 0, stream>>>(centers, cursor, perm, P);
  k_permute<<<(P*16 + 255)/256, 256, 0, stream>>>(sh, rb, nbrs, perm, edge_ph, nbrp, P);
  k_inv    <<<N,                256, 0, stream>>>(sh, rb, cemb, nbrs, offsets, perm, featsA);
  k_tp     <<<N,                256, 0, stream>>>(featsA, cg_d);
  k_halfg  <<<(N*GSTR + 255)/256, 256, 0, stream>>>(featsA, cemb, featsAg, N);
  k_eq2    <<<N,               1024, 0, stream>>>(edge_ph, nbrp, offsets, featsAg, featsB, cg_d);
  k_eq2_nofg<<<N,              1024, 0, stream>>>(edge_ph, offsets, featsA, cg_d);   // diagnostic
  k_tp     <<<N,                256, 0, stream>>>(featsB, cg_d);
  k_energy <<<(N + 3)/4,        256, 0, stream>>>(featsB, cemb, wE, bE, (float*)d_out, N);
}

// Round 11
// 4951.325 us; speedup vs baseline: 1.0384x; 1.0384x over previous
//
#include <hip/hip_runtime.h>
#include <vector>
#include <cmath>
#include <cstdint>

// ---------------- static model tables (constexpr, device-usable) ----------------
constexpr int KLc[4]  = {256,192,128,64};     // k_max per l
constexpr int NMLc[4] = {8,6,4,2};            // radial basis per l
constexpr int SHBc[5] = {0,1,4,9,16};         // sh split bases
constexpr int RBBc[5] = {0,8,14,18,20};       // rb split bases
constexpr int FBc[5]  = {0,256,832,1472,1920};// feats flat base per l  (sum (2l+1)*K[l])
constexpr int NCMB = 34, CGTOT = 3436, FTOT = 1920;

struct Combos { int l1[NCMB], l2[NCMB], L[NCMB], cgoff[NCMB], kk[NCMB]; };
constexpr Combos make_combos(){
  Combos c{}; int n=0, cg=0;
  for(int a=0;a<=3;a++)for(int b=0;b<=3;b++){
    int lo=a>b?a-b:b-a, hi=(a+b<3)?(a+b):3;
    for(int L=lo;L<=hi;L++){
      c.l1[n]=a; c.l2[n]=b; c.L[n]=L; c.cgoff[n]=cg;
      int mx=a>b?a:b; if(L>mx) mx=L; c.kk[n]=KLc[mx];          // TP truncation (min of all three)
      cg+=(2*a+1)*(2*b+1)*(2*L+1); n++;
    }
  }
  return c;
}
constexpr Combos CB = make_combos();
static_assert(CB.cgoff[NCMB-1] + 7*7*7 == CGTOT, "cg size");

struct Grp { int cnt[4]; int list[4][12]; };
constexpr Grp make_Lg(){ Grp g{}; for(int i=0;i<NCMB;i++){ int L=CB.L[i]; g.list[L][g.cnt[L]++]=i; } return g; }
constexpr Grp LG = make_Lg();     // combos grouped by output L (for k_tp)

struct Rows { int sh[64], rb[64], off[64]; };
constexpr Rows make_rows(){ Rows r{}; int i=0;
  for(int l=0;l<4;l++)for(int m=0;m<2*l+1;m++)for(int n=0;n<NMLc[l];n++){
    r.sh[i]=SHBc[l]+m; r.rb[i]=RBBc[l]+n; r.off[i]=FBc[l]+m*KLc[l]+n*32; i++; }
  for(;i<64;i++){ r.sh[i]=0; r.rb[i]=0; r.off[i]=0; }
  return r; }
constexpr Rows RWS = make_rows();  // 60 (l,m,n) rows for invariant MP

// ---------------- k_eq tables: S-factorization, UNIFORM pair-loop layout ----------------
constexpr int NSL=425, NG=16, RPAD=149; // RPAD odd -> 2-way bank aliasing (free)
constexpr int DEPTH=6;                  // fg prefetch depth (rotating slots)
constexpr int NTILE=30;
constexpr int GSTR=1024;                // featsAg per-atom stride in dwords (4096 B)

constexpr int iabs_(int x){ return x<0?-x:x; }
__host__ __device__ constexpr bool sl_valid(int l1,int l2,int kt){ return l2<=3-kt && iabs_(l1-l2)<=3-kt; }

__host__ __device__ constexpr int rb_base(int kt,int l1,int l2){
  int base=0;
  for(int p=0;p<4;p++)for(int q=0;q<4;q++){
    if(p==l1 && q==l2) return base;
    if(sl_valid(p,q,kt)) base += (2*p+1)*(2*q+1);
  }
  return base;
}

struct EqTab {
  short       srow[NG][32];   // stage row within its dump phase (-1 = pad slot)
  signed char sph [NG][32];   // dump phase 0..4 (-1 = pad slot)
  int nr[NG];                 // tiles in group (1 or 2)
  short roff[NG][2];          // fg row offsets into feats (element units); [1]==[0] if nr==1
  int total;
};
constexpr EqTab make_eqtab(){
  EqTab T{};
  for(int g=0;g<NG;g++){
    for(int s=0;s<32;s++){ T.srow[g][s]=-1; T.sph[g][s]=-1; }
    T.nr[g]=0; T.roff[g][0]=0; T.roff[g][1]=0;
  }
  int tl2[NTILE]{}, tkt[NTILE]{}, tbb[NTILE]{}, tsz[NTILE]{}; int nt=0;
  for(int l2=0;l2<4;l2++)for(int kt=0;kt<4-l2;kt++)for(int b=0;b<2*l2+1;b++){
    int sz=0;
    for(int l1=0;l1<4;l1++) if(sl_valid(l1,l2,kt)) sz+=2*l1+1;
    tl2[nt]=l2; tkt[nt]=kt; tbb[nt]=b; tsz[nt]=sz; nt++;
  }
  bool used[NTILE]{}; int gload[NG]{}; int gcnt[NG]{}; int gt[NG][2]{};
  for(int it=0; it<nt; it++){
    int best=-1;
    for(int i=0;i<nt;i++) if(!used[i] && (best<0 || tsz[i]>tsz[best])) best=i;
    used[best]=true;
    int g=-1;
    for(int j=0;j<NG;j++) if(gcnt[j]<2 && (g<0 || gload[j]<gload[g])) g=j;
    gt[g][gcnt[g]]=best; gcnt[g]++; gload[g]+=tsz[best];
  }
  int total=0;
  for(int g=0;g<NG;g++){
    T.nr[g]=gcnt[g];
    for(int tk=0;tk<gcnt[g];tk++){
      const int ti=gt[g][tk];
      const int l2=tl2[ti], kt=tkt[ti], b=tbb[ti];
      T.roff[g][tk]=(short)(FBc[l2]+b*KLc[l2]+kt*64);
      for(int i=0;i<16;i++){
        const int l1=(i==0)?0:(i<4)?1:(i<9)?2:3;
        const int aa=i-SHBc[l1];
        if(!sl_valid(l1,l2,kt)) continue;
        const int s=tk*16+i;
        const int rbi=rb_base(kt,l1,l2)+aa*(2*l2+1)+b;
        int ph, sr;
        if(kt==0){ if(l1<=2){ ph=0; sr=rbi; } else { ph=1; sr=rbi-144; } }
        else { ph=kt+1; sr=rbi; }
        T.sph[g][s]=(signed char)ph; T.srow[g][s]=(short)sr;
        total++;
      }
    }
    if(gcnt[g]==1) T.roff[g][1]=T.roff[g][0];   // duplicate load, acc[16..31] never staged
  }
  T.total=total;
  return T;
}
constexpr EqTab ET = make_eqtab();
static_assert(ET.total==NSL, "slice count");
constexpr bool chk_srow(){ for(int g=0;g<NG;g++) for(int s=0;s<32;s++) if(ET.srow[g][s]>=RPAD) return false; return true; }
static_assert(chk_srow(), "stage rows fit RPAD");

// wave-uniform row offsets (flat arrays, runtime-indexed by group)
struct RoffA { int r0[NG]; int r1[NG]; };
constexpr RoffA make_roffa(){ RoffA R{}; for(int g=0;g<NG;g++){ R.r0[g]=ET.roff[g][0]; R.r1[g]=ET.roff[g][1]; } return R; }
constexpr RoffA RFA = make_roffa();

// contraction combo -> group assignment (greedy by cost n1*n2*nL)
struct CAsg { int cnt[NG]; unsigned char ci[NG][8]; };
constexpr CAsg make_casg(){
  CAsg C{}; bool used[NCMB]{}; int load[NG]{};
  for(int it=0; it<NCMB; it++){
    int best=-1, bc=-1;
    for(int i=0;i<NCMB;i++) if(!used[i]){
      int c=(2*CB.l1[i]+1)*(2*CB.l2[i]+1)*(2*CB.L[i]+1);
      if(c>bc){bc=c;best=i;}
    }
    used[best]=true;
    int g=0; for(int j=1;j<NG;j++) if(load[j]<load[g]) g=j;
    C.ci[g][C.cnt[g]++]=(unsigned char)best; load[g]+=bc;
  }
  return C;
}
constexpr CAsg CA = make_casg();
constexpr bool chk_ca(){ for(int g=0;g<NG;g++) if(CA.cnt[g]>8) return false; return true; }
static_assert(chk_ca(), "CA cap");

__host__ __device__ constexpr bool combo_in_phase(int ci,int ph){
  int l1=CB.l1[ci], l2=CB.l2[ci], L=CB.L[ci];
  if(ph==0) return l1<=2;
  if(ph==1) return l1==3;
  int kt=ph-1;
  return (l2<=3-kt) && (L<=3-kt);
}
__host__ __device__ constexpr int phase_kt(int ph){ return ph<=1?0:ph-1; }
__host__ __device__ constexpr int phase_rbadj(int ph){ return ph==1?144:0; }

// ---------------- host: numpy-legacy RandomState(0) CG generation ----------------
namespace nprng {
struct MT {
  uint32_t mt[624]; int mti; bool has_g; double g;
  void seed(uint32_t s){ for(int i=0;i<624;i++){ mt[i]=s; s=1812433253u*(s^(s>>30))+(uint32_t)i+1u; } mti=624; has_g=false; g=0.0; }
  uint32_t u32(){
    if(mti>=624){
      for(int i=0;i<624;i++){
        uint32_t y=(mt[i]&0x80000000u)|(mt[(i+1)%624]&0x7fffffffu);
        mt[i]=mt[(i+397)%624]^(y>>1)^((y&1u)?0x9908b0dfu:0u);
      }
      mti=0;
    }
    uint32_t y=mt[mti++];
    y^=y>>11; y^=(y<<7)&0x9d2c5680u; y^=(y<<15)&0xefc60000u; y^=y>>18;
    return y;
  }
  double dbl(){ uint32_t a=u32()>>5, b=u32()>>6; return (a*67108864.0+b)/9007199254740992.0; }
  double gauss(){
    if(has_g){ has_g=false; return g; }
    double f,x1,x2,r2;
    do{ x1=2.0*dbl()-1.0; x2=2.0*dbl()-1.0; r2=x1*x1+x2*x2; }while(r2>=1.0||r2==0.0);
    f=sqrt(-2.0*log(r2)/r2);
    g=f*x1; has_g=true; return f*x2;
  }
};
}
static std::vector<float> build_cg(){
  nprng::MT r; r.seed(0);
  std::vector<float> v; v.reserve(CGTOT);
  for(int l1=0;l1<=3;l1++)for(int l2=0;l2<=3;l2++){
    int lo = l1>l2? l1-l2 : l2-l1;
    int hi = (l1+l2<3)? (l1+l2) : 3;
    for(int L=lo;L<=hi;L++){
      int n=(2*l1+1)*(2*l2+1)*(2*L+1);
      for(int i=0;i<n;i++) v.push_back((float)(r.gauss()*0.2));
    }
  }
  return v;
}

// ---------------- small setup kernels ----------------
__global__ __launch_bounds__(256) void k_cemb(const float* __restrict__ emb_table,
    const int* __restrict__ species, float* __restrict__ cemb, int* __restrict__ counts, int N){
  int i = blockIdx.x*256 + threadIdx.x;
  if(i < N) counts[i] = 0;
  if(i < N*32){ int n = i>>5, c = i&31; cemb[i] = emb_table[species[n]*32 + c]; }
}

__global__ __launch_bounds__(256) void k_hist(const int* __restrict__ centers, int* counts, int P){
  int i = blockIdx.x*256 + threadIdx.x;
  if(i < P) atomicAdd(&counts[centers[i]], 1);
}

__global__ __launch_bounds__(256) void k_scan(const int* __restrict__ counts,
    int* __restrict__ offsets, int* __restrict__ cursor, int N){
  __shared__ int part[256];
  const int t = threadIdx.x;
  const int CH = (N + 255)/256;
  const int lo = t*CH;
  int hi = (t+1)*CH; if(hi > N) hi = N;
  int s = 0;
  for(int i=lo;i<hi;i++) s += counts[i];
  part[t] = s; __syncthreads();
  const int own = s;
  for(int d=1; d<256; d<<=1){
    int v = (t>=d)? part[t-d] : 0;
    __syncthreads();
    part[t] += v;
    __syncthreads();
  }
  int run = part[t] - own;
  for(int i=lo;i<hi;i++){ offsets[i]=run; cursor[i]=run; run += counts[i]; }
  if(t==255) offsets[N] = part[255];
}

__global__ __launch_bounds__(256) void k_scatter(const int* __restrict__ centers,
    int* cursor, int* __restrict__ perm, int P){
  int i = blockIdx.x*256 + threadIdx.x;
  if(i < P){ int c = centers[i]; int pos = atomicAdd(&cursor[c], 1); perm[pos] = i; }
}

// ---------------- pair-order precompute: PACKED FP16 edge components + neighbor ids ----
// edge_ph[pos*16+i] = fp16( sh[p*16+i] * 0.1 * sum(rb[p, l-range(i)]) )
__global__ __launch_bounds__(256) void k_permute(const float* __restrict__ sh,
    const float* __restrict__ rb, const int* __restrict__ nbrs, const int* __restrict__ perm,
    unsigned short* __restrict__ edge_ph, int* __restrict__ nbrp, int P){
  int u = blockIdx.x*256 + threadIdx.x;
  int pos = u>>4, i = u&15;
  if(pos >= P) return;
  int p = perm[pos];
  if(i==0) nbrp[pos] = nbrs[p];
  int l = (i==0)?0:(i<4)?1:(i<9)?2:3;
  float s=0.f;
  for(int n=RBBc[l]; n<RBBc[l+1]; n++) s += rb[p*20+n];
  float e = sh[p*16+i]*0.1f*s;   // sh * NU_SCALING * rb.sum
  _Float16 h = (_Float16)e;
  edge_ph[(size_t)pos*16+i] = *(unsigned short*)&h;
}

// ---------------- grouped fp16 gather table, neighbor-embedding BAKED IN ------------
// featsAg[n][g][r][i] (stride GSTR dwords = 4096 B/atom) = fp16(featsA[n][roff(g,r)+i] * cemb[n][i&31])
__global__ __launch_bounds__(256) void k_halfg(const float* __restrict__ src,
    const float* __restrict__ cemb, unsigned int* __restrict__ dst, int N){
  int u = blockIdx.x*256 + threadIdx.x;
  if(u >= N*GSTR) return;
  int n = u >> 10, o = u & 1023;          // o: dword within atom record
  int g = o >> 6, i = o & 63;             // g: wave group, i: lane
  float c = cemb[n*32 + (i&31)];
  float v0 = src[(size_t)n*FTOT + RFA.r0[g] + i] * c;
  float v1 = src[(size_t)n*FTOT + RFA.r1[g] + i] * c;
  _Float16 h0 = (_Float16)v0, h1 = (_Float16)v1;
  unsigned int lo = *(unsigned short*)&h0, hi = *(unsigned short*)&h1;
  dst[u] = lo | (hi<<16);
}

// ---------------- invariant MP (batched pairs, 3 barriers / 8 pairs) ----------------
__global__ __launch_bounds__(256) void k_inv(const float* __restrict__ sh, const float* __restrict__ rb,
    const float* __restrict__ cemb, const int* __restrict__ nbrs, const int* __restrict__ offsets,
    const int* __restrict__ perm, float* __restrict__ feats){
  const int a = blockIdx.x, t = threadIdx.x;
  __shared__ float sh_s[8][16], rb_s[8][20], emb_s[8][32], shrb_s[8][60];
  const int c = t & 31, rg = t >> 5;
  float acc[8];
  #pragma unroll
  for(int j=0;j<8;j++) acc[j] = 0.f;
  const int beg = offsets[a], cnt = offsets[a+1]-beg;
  for(int jb=0; jb<cnt; jb+=8){
    __syncthreads();
    for(int u=t; u<8*36; u+=256){
      int j=u/36, i=u-36*j;
      if(jb+j<cnt){
        int p=perm[beg+jb+j];
        if(i<16) sh_s[j][i]=sh[p*16+i]*0.1f;      // NU_SCALING
        else     rb_s[j][i-16]=rb[p*20+i-16];
      }
    }
    for(int u=t; u<8*32; u+=256){
      int j=u>>5, i=u&31;
      if(jb+j<cnt){ int nb=nbrs[perm[beg+jb+j]]; emb_s[j][i]=cemb[(size_t)nb*32+i]; }
    }
    __syncthreads();
    for(int u=t; u<8*60; u+=256){
      int j=u/60, r=u-60*j;
      if(jb+j<cnt) shrb_s[j][r] = sh_s[j][RWS.sh[r]] * rb_s[j][RWS.rb[r]];
    }
    __syncthreads();
    const int jm = (cnt-jb<8)?(cnt-jb):8;
    for(int j=0;j<jm;j++){
      const float e = emb_s[j][c];
      #pragma unroll
      for(int q=0;q<8;q++){ int r=rg+8*q; if(r<60) acc[q]=fmaf(shrb_s[j][r], e, acc[q]); }
    }
  }
  #pragma unroll
  for(int q=0;q<8;q++){
    int r = rg + 8*q;
    if(r < 60) feats[(size_t)a*FTOT + RWS.off[r] + c] = 0.1f * acc[q];  // MP_SCALING
  }
}

// ---------------- CG iterate (in-place): feats = feats + 0.1 * TP(feats, feats) ----------------
__device__ __forceinline__ float cg_u(const float* __restrict__ cg, int idx){
  return cg[__builtin_amdgcn_readfirstlane(idx)];
}
__global__ __launch_bounds__(256) void k_tp(float* __restrict__ feats, const float* __restrict__ cg){
  const int a = blockIdx.x, t = threadIdx.x;
  __shared__ float f_s[FTOT];
  float* fa = feats + (size_t)a*FTOT;
  for(int i=t;i<FTOT;i+=256)  f_s[i]  = fa[i];
  __syncthreads();
  #pragma unroll
  for(int L=0; L<4; L++){
    const int KLL = KLc[L], nL = 2*L+1;
    const int nel = nL*KLL;
    for(int e=t; e<nel; e+=256){
      const int M = e / KLL, k = e - M*KLL;
      float acc = 0.f;
      #pragma unroll
      for(int gi=0; gi<LG.cnt[L]; gi++){
        const int ci = LG.list[L][gi];
        const int l1 = CB.l1[ci], l2 = CB.l2[ci];
        if(k < CB.kk[ci]){
          const int n2 = 2*l2+1;
          #pragma unroll
          for(int aa=0; aa<2*l1+1; aa++){
            const float Av = f_s[FBc[l1] + aa*KLc[l1] + k];
            #pragma unroll
            for(int b=0; b<n2; b++)
              acc += cg_u(cg, CB.cgoff[ci] + (aa*n2+b)*nL + M) * (Av * f_s[FBc[l2] + b*KLc[l2] + k]);
          }
        }
      }
      fa[FBc[L] + M*KLL + k] = f_s[FBc[L] + M*KLL + k] + 0.1f*acc;   // NU_SCALING residual
    }
  }
}

// ---------------- equivariant MP v14: named-register fp16 edges + readlane (no addr-taken) ----------------
template<int G,int PH,int U>
__device__ __forceinline__ void contract_combos(const float* __restrict__ stageT,
    float* __restrict__ out_s, const float* __restrict__ cg, int lane){
  if constexpr (U < CA.cnt[G]) {
    constexpr int ci = CA.ci[G][U];
    if constexpr (combo_in_phase(ci,PH)) {
      constexpr int l1=CB.l1[ci], l2=CB.l2[ci], L=CB.L[ci];
      constexpr int n1=2*l1+1, n2=2*l2+1, nL=2*L+1;
      constexpr int kt=phase_kt(PH);
      constexpr int rbase = rb_base(kt,l1,l2) - phase_rbadj(PH);
      float oa[nL];
      #pragma unroll
      for(int M=0;M<nL;M++) oa[M]=0.f;
      #pragma unroll
      for(int aa=0;aa<n1;aa++){
        #pragma unroll
        for(int b=0;b<n2;b++){
          const float sv = stageT[lane*RPAD + rbase + aa*n2 + b];
          #pragma unroll
          for(int M=0;M<nL;M++)
            oa[M] = fmaf(cg[CB.cgoff[ci] + (aa*n2+b)*nL + M], sv, oa[M]);  // uniform idx -> s_load
        }
      }
      #pragma unroll
      for(int M=0;M<nL;M++)
        atomicAdd(&out_s[FBc[L] + M*KLc[L] + kt*64 + lane], oa[M]);
    }
    contract_combos<G,PH,U+1>(stageT,out_s,cg,lane);
  }
}

template<int G,int PH>
__device__ __forceinline__ void eq_phase(const float* acc, float* stageT, float* out_s,
    const float* __restrict__ cg, int lane){
  __syncthreads();                       // protect previous phase's stage reads
  #pragma unroll
  for(int s=0;s<32;s++){
    if(ET.sph[G][s]==PH) stageT[lane*RPAD + ET.srow[G][s]] = acc[s];  // constexpr-folded
  }
  __syncthreads();
  contract_combos<G,PH,0>(stageT,out_s,cg,lane);
}

template<int G>
__device__ __forceinline__ void eq_phases(const float* acc, float* stageT, float* out_s,
    const float* __restrict__ cg, int lane){
  eq_phase<G,0>(acc,stageT,out_s,cg,lane);
  eq_phase<G,1>(acc,stageT,out_s,cg,lane);
  eq_phase<G,2>(acc,stageT,out_s,cg,lane);
  eq_phase<G,3>(acc,stageT,out_s,cg,lane);
  eq_phase<G,4>(acc,stageT,out_s,cg,lane);
}

// one packed-fp16 edge dword, extracted from lane q (uniform) -> SGPR, 4 fmas.
// NOTE: ed passed BY VALUE (never address-taken) -> stays in a VGPR.
__device__ __forceinline__ void eq_edge_fma(unsigned ed, int q, float f0, float f1,
    float& aL, float& aH, float& bL, float& bH){
  const unsigned d = (unsigned)__builtin_amdgcn_readlane((int)ed, q);
  union { unsigned short s; _Float16 h; } lo, hi;
  lo.s = (unsigned short)(d & 0xffffu);
  hi.s = (unsigned short)(d >> 16);
  const float el = (float)lo.h, eh = (float)hi.h;   // v_cvt_f32_f16 (SGPR src ok)
  aL = fmaf(el, f0, aL);
  aH = fmaf(eh, f0, aH);
  bL = fmaf(el, f1, bL);
  bH = fmaf(eh, f1, bH);
}

__global__ __launch_bounds__(1024,8) void k_eq2(const unsigned short* __restrict__ edge_ph,
    const int* __restrict__ nbrp, const int* __restrict__ offsets,
    const unsigned int* __restrict__ featsAg,
    float* __restrict__ featsB, const float* __restrict__ cg){
  __shared__ float stageT[64*RPAD];   // 38144 B, odd lane stride -> conflict-free
  __shared__ float out_s[FTOT];       // 7680 B
  const int a = blockIdx.x, t = threadIdx.x, lane = t&63, g = t>>6;

  float acc[32];
  #pragma unroll
  for(int s=0;s<32;s++) acc[s]=0.f;
  for(int i=t;i<FTOT;i+=1024) out_s[i]=0.f;
  const int beg = offsets[a], cnt = offsets[a+1]-beg;

  for(int jb=0; jb<cnt; jb+=64){
    const int jm = (cnt-jb<64)?(cnt-jb):64;
    // batch state: lane l holds pair (jb+l)'s nb + 16 packed-fp16 edges as EIGHT NAMED dwords
    int pofs = jb + lane; if(pofs > cnt-1) pofs = cnt-1;
    const int nbv = nbrp[beg + pofs];
    const uint4 tA = *(const uint4*)(edge_ph + (size_t)(beg+pofs)*16);
    const uint4 tB = *(const uint4*)(edge_ph + (size_t)(beg+pofs)*16 + 8);
    const unsigned e0=tA.x, e1=tA.y, e2=tA.z, e3=tA.w;
    const unsigned e4=tB.x, e5=tB.y, e6=tB.z, e7=tB.w;

    // fg prefetch slots (vmcnt-pipelined; addresses via readlane -> SGPR base + t)
    unsigned int fgS[DEPTH];
    #pragma unroll
    for(int s=0;s<DEPTH;s++){
      int qq = (s<jm)? s : jm-1;
      unsigned nb = (unsigned)__builtin_amdgcn_readlane(nbv, qq);
      fgS[s] = featsAg[(size_t)nb*GSTR + t];
    }
    for(int j=0;j<jm;j+=DEPTH){
      #pragma unroll
      for(int s=0;s<DEPTH;s++){
        const int q = j+s;
        if(q < jm){
          const unsigned int v = fgS[s];        // counted vmcnt wait (compiler)
          const int qn = q + DEPTH;
          if(qn < jm){                           // refill slot with pair DEPTH ahead
            unsigned nb = (unsigned)__builtin_amdgcn_readlane(nbv, qn);
            fgS[s] = featsAg[(size_t)nb*GSTR + t];
          }
          union { unsigned int u; _Float16 h[2]; } cv; cv.u = v;
          const float f0 = (float)cv.h[0], f1 = (float)cv.h[1];
          eq_edge_fma(e0,q,f0,f1, acc[0], acc[1], acc[16],acc[17]);
          eq_edge_fma(e1,q,f0,f1, acc[2], acc[3], acc[18],acc[19]);
          eq_edge_fma(e2,q,f0,f1, acc[4], acc[5], acc[20],acc[21]);
          eq_edge_fma(e3,q,f0,f1, acc[6], acc[7], acc[22],acc[23]);
          eq_edge_fma(e4,q,f0,f1, acc[8], acc[9], acc[24],acc[25]);
          eq_edge_fma(e5,q,f0,f1, acc[10],acc[11],acc[26],acc[27]);
          eq_edge_fma(e6,q,f0,f1, acc[12],acc[13],acc[28],acc[29]);
          eq_edge_fma(e7,q,f0,f1, acc[14],acc[15],acc[30],acc[31]);
        }
      }
    }
  }

  // once-per-block contract phases (each begins with __syncthreads -> covers out_s init)
  switch(g){
    case 0:  eq_phases<0 >(acc,stageT,out_s,cg,lane); break;
    case 1:  eq_phases<1 >(acc,stageT,out_s,cg,lane); break;
    case 2:  eq_phases<2 >(acc,stageT,out_s,cg,lane); break;
    case 3:  eq_phases<3 >(acc,stageT,out_s,cg,lane); break;
    case 4:  eq_phases<4 >(acc,stageT,out_s,cg,lane); break;
    case 5:  eq_phases<5 >(acc,stageT,out_s,cg,lane); break;
    case 6:  eq_phases<6 >(acc,stageT,out_s,cg,lane); break;
    case 7:  eq_phases<7 >(acc,stageT,out_s,cg,lane); break;
    case 8:  eq_phases<8 >(acc,stageT,out_s,cg,lane); break;
    case 9:  eq_phases<9 >(acc,stageT,out_s,cg,lane); break;
    case 10: eq_phases<10>(acc,stageT,out_s,cg,lane); break;
    case 11: eq_phases<11>(acc,stageT,out_s,cg,lane); break;
    case 12: eq_phases<12>(acc,stageT,out_s,cg,lane); break;
    case 13: eq_phases<13>(acc,stageT,out_s,cg,lane); break;
    case 14: eq_phases<14>(acc,stageT,out_s,cg,lane); break;
    default: eq_phases<15>(acc,stageT,out_s,cg,lane); break;
  }
  __syncthreads();
  float* ob = featsB + (size_t)a*FTOT;
  for(int i=t;i<FTOT;i+=1024) ob[i] = 0.1f*out_s[i];       // MP_SCALING
}

// ---------------- energy readout ----------------
__global__ __launch_bounds__(256) void k_energy(const float* __restrict__ feats,
    const float* __restrict__ cemb, const float* __restrict__ wE, const float* __restrict__ bE,
    float* __restrict__ out, int N){
  const int wid = threadIdx.x >> 6, lane = threadIdx.x & 63;
  const int a = blockIdx.x*4 + wid;
  if(a >= N) return;
  const float e = cemb[(size_t)a*32 + (lane & 31)];
  float s = 0.f;
  for(int k=lane; k<256; k+=64) s += feats[(size_t)a*FTOT + k] * e * wE[k];
  #pragma unroll
  for(int off=32; off; off>>=1) s += __shfl_down(s, off, 64);
  if(lane == 0) out[a] = s + bE[0];
}

// ---------------- launcher ----------------
extern "C" void kernel_launch(void* const* d_in, const int* in_sizes, int n_in,
                              void* d_out, int out_size, void* d_ws, size_t ws_size,
                              hipStream_t stream){
  const float* sh        = (const float*)d_in[0];
  const float* rb        = (const float*)d_in[1];
  const float* emb_table = (const float*)d_in[2];
  const float* wE        = (const float*)d_in[3];
  const float* bE        = (const float*)d_in[4];
  const int*   species   = (const int*)d_in[5];
  const int*   centers   = (const int*)d_in[6];
  const int*   nbrs      = (const int*)d_in[7];
  const int N = in_sizes[5];
  const int P = in_sizes[6];

  char* ws = (char*)d_ws; size_t off = 0;
  auto carve = [&](size_t bytes)->void*{
    void* p = ws + off; off = (off + bytes + 255) & ~(size_t)255; return p;
  };
  float* cg_d    = (float*)carve((size_t)CGTOT*4);
  float* cemb    = (float*)carve((size_t)N*32*4);
  int*   counts  = (int*)  carve((size_t)N*4);
  int*   offsets = (int*)  carve((size_t)(N+1)*4);
  int*   cursor  = (int*)  carve((size_t)N*4);
  int*   perm    = (int*)  carve((size_t)P*4);
  unsigned short* edge_ph = (unsigned short*)carve((size_t)P*16*2);
  int*   nbrp    = (int*)  carve((size_t)(P+64)*4);
  float* featsA  = (float*)carve((size_t)N*FTOT*4);
  float* featsB  = (float*)carve((size_t)N*FTOT*4);
  unsigned int* featsAg = (unsigned int*)carve((size_t)N*GSTR*4);
  (void)ws_size; (void)n_in; (void)out_size;

  static const std::vector<float> cg_host = build_cg();  // deterministic; host-side cache only
  hipMemcpyAsync(cg_d, cg_host.data(), (size_t)CGTOT*4, hipMemcpyHostToDevice, stream);

  k_cemb   <<<(N*32 + 255)/256, 256, 0, stream>>>(emb_table, species, cemb, counts, N);
  k_hist   <<<(P + 255)/256,    256, 0, stream>>>(centers, counts, P);
  k_scan   <<<1,                256, 0, stream>>>(counts, offsets, cursor, N);
  k_scatter<<<(P + 255)/256,    256, 0, stream>>>(centers, cursor, perm, P);
  k_permute<<<(P*16 + 255)/256, 256, 0, stream>>>(sh, rb, nbrs, perm, edge_ph, nbrp, P);
  k_inv    <<<N,                256, 0, stream>>>(sh, rb, cemb, nbrs, offsets, perm, featsA);
  k_tp     <<<N,                256, 0, stream>>>(featsA, cg_d);
  k_halfg  <<<(N*GSTR + 255)/256, 256, 0, stream>>>(featsA, cemb, featsAg, N);
  k_eq2    <<<N,               1024, 0, stream>>>(edge_ph, nbrp, offsets, featsAg, featsB, cg_d);
  k_tp     <<<N,                256, 0, stream>>>(featsB, cg_d);
  k_energy <<<(N + 3)/4,        256, 0, stream>>>(featsB, cemb, wE, bE, (float*)d_out, N);
}

// Round 12
// 859.780 us; speedup vs baseline: 5.9798x; 5.7588x over previous
//
#include <hip/hip_runtime.h>
#include <vector>
#include <cmath>
#include <cstdint>

// ---------------- static model tables (constexpr, device-usable) ----------------
constexpr int KLc[4]  = {256,192,128,64};     // k_max per l
constexpr int NMLc[4] = {8,6,4,2};            // radial basis per l
constexpr int SHBc[5] = {0,1,4,9,16};         // sh split bases
constexpr int RBBc[5] = {0,8,14,18,20};       // rb split bases
constexpr int FBc[5]  = {0,256,832,1472,1920};// feats flat base per l  (sum (2l+1)*K[l])
constexpr int NCMB = 34, CGTOT = 3436, FTOT = 1920;

struct Combos { int l1[NCMB], l2[NCMB], L[NCMB], cgoff[NCMB], kk[NCMB]; };
constexpr Combos make_combos(){
  Combos c{}; int n=0, cg=0;
  for(int a=0;a<=3;a++)for(int b=0;b<=3;b++){
    int lo=a>b?a-b:b-a, hi=(a+b<3)?(a+b):3;
    for(int L=lo;L<=hi;L++){
      c.l1[n]=a; c.l2[n]=b; c.L[n]=L; c.cgoff[n]=cg;
      int mx=a>b?a:b; if(L>mx) mx=L; c.kk[n]=KLc[mx];          // TP truncation (min of all three)
      cg+=(2*a+1)*(2*b+1)*(2*L+1); n++;
    }
  }
  return c;
}
constexpr Combos CB = make_combos();
static_assert(CB.cgoff[NCMB-1] + 7*7*7 == CGTOT, "cg size");

struct Grp { int cnt[4]; int list[4][12]; };
constexpr Grp make_Lg(){ Grp g{}; for(int i=0;i<NCMB;i++){ int L=CB.L[i]; g.list[L][g.cnt[L]++]=i; } return g; }
constexpr Grp LG = make_Lg();     // combos grouped by output L (for k_tp)

struct Rows { int sh[64], rb[64], off[64]; };
constexpr Rows make_rows(){ Rows r{}; int i=0;
  for(int l=0;l<4;l++)for(int m=0;m<2*l+1;m++)for(int n=0;n<NMLc[l];n++){
    r.sh[i]=SHBc[l]+m; r.rb[i]=RBBc[l]+n; r.off[i]=FBc[l]+m*KLc[l]+n*32; i++; }
  for(;i<64;i++){ r.sh[i]=0; r.rb[i]=0; r.off[i]=0; }
  return r; }
constexpr Rows RWS = make_rows();  // 60 (l,m,n) rows for invariant MP

// ---------------- k_eq tables: S-factorization, UNIFORM pair-loop layout ----------------
constexpr int NSL=425, NG=16, RPAD=149; // RPAD odd -> 2-way bank aliasing (free)
constexpr int DEPTH=8;                  // fg prefetch depth (rotating slots)
constexpr int NTILE=30;
constexpr int GSTR=1024;                // featsAg per-atom stride in dwords (4096 B)

constexpr int iabs_(int x){ return x<0?-x:x; }
__host__ __device__ constexpr bool sl_valid(int l1,int l2,int kt){ return l2<=3-kt && iabs_(l1-l2)<=3-kt; }

__host__ __device__ constexpr int rb_base(int kt,int l1,int l2){
  int base=0;
  for(int p=0;p<4;p++)for(int q=0;q<4;q++){
    if(p==l1 && q==l2) return base;
    if(sl_valid(p,q,kt)) base += (2*p+1)*(2*q+1);
  }
  return base;
}

struct EqTab {
  short       srow[NG][32];   // stage row within its dump phase (-1 = pad slot)
  signed char sph [NG][32];   // dump phase 0..4 (-1 = pad slot)
  int nr[NG];                 // tiles in group (1 or 2)
  short roff[NG][2];          // fg row offsets into feats (element units); [1]==[0] if nr==1
  int total;
};
constexpr EqTab make_eqtab(){
  EqTab T{};
  for(int g=0;g<NG;g++){
    for(int s=0;s<32;s++){ T.srow[g][s]=-1; T.sph[g][s]=-1; }
    T.nr[g]=0; T.roff[g][0]=0; T.roff[g][1]=0;
  }
  int tl2[NTILE]{}, tkt[NTILE]{}, tbb[NTILE]{}, tsz[NTILE]{}; int nt=0;
  for(int l2=0;l2<4;l2++)for(int kt=0;kt<4-l2;kt++)for(int b=0;b<2*l2+1;b++){
    int sz=0;
    for(int l1=0;l1<4;l1++) if(sl_valid(l1,l2,kt)) sz+=2*l1+1;
    tl2[nt]=l2; tkt[nt]=kt; tbb[nt]=b; tsz[nt]=sz; nt++;
  }
  bool used[NTILE]{}; int gload[NG]{}; int gcnt[NG]{}; int gt[NG][2]{};
  for(int it=0; it<nt; it++){
    int best=-1;
    for(int i=0;i<nt;i++) if(!used[i] && (best<0 || tsz[i]>tsz[best])) best=i;
    used[best]=true;
    int g=-1;
    for(int j=0;j<NG;j++) if(gcnt[j]<2 && (g<0 || gload[j]<gload[g])) g=j;
    gt[g][gcnt[g]]=best; gcnt[g]++; gload[g]+=tsz[best];
  }
  int total=0;
  for(int g=0;g<NG;g++){
    T.nr[g]=gcnt[g];
    for(int tk=0;tk<gcnt[g];tk++){
      const int ti=gt[g][tk];
      const int l2=tl2[ti], kt=tkt[ti], b=tbb[ti];
      T.roff[g][tk]=(short)(FBc[l2]+b*KLc[l2]+kt*64);
      for(int i=0;i<16;i++){
        const int l1=(i==0)?0:(i<4)?1:(i<9)?2:3;
        const int aa=i-SHBc[l1];
        if(!sl_valid(l1,l2,kt)) continue;
        const int s=tk*16+i;
        const int rbi=rb_base(kt,l1,l2)+aa*(2*l2+1)+b;
        int ph, sr;
        if(kt==0){ if(l1<=2){ ph=0; sr=rbi; } else { ph=1; sr=rbi-144; } }
        else { ph=kt+1; sr=rbi; }
        T.sph[g][s]=(signed char)ph; T.srow[g][s]=(short)sr;
        total++;
      }
    }
    if(gcnt[g]==1) T.roff[g][1]=T.roff[g][0];   // duplicate load, acc[16..31] never staged
  }
  T.total=total;
  return T;
}
constexpr EqTab ET = make_eqtab();
static_assert(ET.total==NSL, "slice count");
constexpr bool chk_srow(){ for(int g=0;g<NG;g++) for(int s=0;s<32;s++) if(ET.srow[g][s]>=RPAD) return false; return true; }
static_assert(chk_srow(), "stage rows fit RPAD");

// wave-uniform row offsets (flat arrays, runtime-indexed by group)
struct RoffA { int r0[NG]; int r1[NG]; };
constexpr RoffA make_roffa(){ RoffA R{}; for(int g=0;g<NG;g++){ R.r0[g]=ET.roff[g][0]; R.r1[g]=ET.roff[g][1]; } return R; }
constexpr RoffA RFA = make_roffa();

// contraction combo -> group assignment (greedy by cost n1*n2*nL)
struct CAsg { int cnt[NG]; unsigned char ci[NG][8]; };
constexpr CAsg make_casg(){
  CAsg C{}; bool used[NCMB]{}; int load[NG]{};
  for(int it=0; it<NCMB; it++){
    int best=-1, bc=-1;
    for(int i=0;i<NCMB;i++) if(!used[i]){
      int c=(2*CB.l1[i]+1)*(2*CB.l2[i]+1)*(2*CB.L[i]+1);
      if(c>bc){bc=c;best=i;}
    }
    used[best]=true;
    int g=0; for(int j=1;j<NG;j++) if(load[j]<load[g]) g=j;
    C.ci[g][C.cnt[g]++]=(unsigned char)best; load[g]+=bc;
  }
  return C;
}
constexpr CAsg CA = make_casg();
constexpr bool chk_ca(){ for(int g=0;g<NG;g++) if(CA.cnt[g]>8) return false; return true; }
static_assert(chk_ca(), "CA cap");

__host__ __device__ constexpr bool combo_in_phase(int ci,int ph){
  int l1=CB.l1[ci], l2=CB.l2[ci], L=CB.L[ci];
  if(ph==0) return l1<=2;
  if(ph==1) return l1==3;
  int kt=ph-1;
  return (l2<=3-kt) && (L<=3-kt);
}
__host__ __device__ constexpr int phase_kt(int ph){ return ph<=1?0:ph-1; }
__host__ __device__ constexpr int phase_rbadj(int ph){ return ph==1?144:0; }

// ---------------- host: numpy-legacy RandomState(0) CG generation ----------------
namespace nprng {
struct MT {
  uint32_t mt[624]; int mti; bool has_g; double g;
  void seed(uint32_t s){ for(int i=0;i<624;i++){ mt[i]=s; s=1812433253u*(s^(s>>30))+(uint32_t)i+1u; } mti=624; has_g=false; g=0.0; }
  uint32_t u32(){
    if(mti>=624){
      for(int i=0;i<624;i++){
        uint32_t y=(mt[i]&0x80000000u)|(mt[(i+1)%624]&0x7fffffffu);
        mt[i]=mt[(i+397)%624]^(y>>1)^((y&1u)?0x9908b0dfu:0u);
      }
      mti=0;
    }
    uint32_t y=mt[mti++];
    y^=y>>11; y^=(y<<7)&0x9d2c5680u; y^=(y<<15)&0xefc60000u; y^=y>>18;
    return y;
  }
  double dbl(){ uint32_t a=u32()>>5, b=u32()>>6; return (a*67108864.0+b)/9007199254740992.0; }
  double gauss(){
    if(has_g){ has_g=false; return g; }
    double f,x1,x2,r2;
    do{ x1=2.0*dbl()-1.0; x2=2.0*dbl()-1.0; r2=x1*x1+x2*x2; }while(r2>=1.0||r2==0.0);
    f=sqrt(-2.0*log(r2)/r2);
    g=f*x1; has_g=true; return f*x2;
  }
};
}
static std::vector<float> build_cg(){
  nprng::MT r; r.seed(0);
  std::vector<float> v; v.reserve(CGTOT);
  for(int l1=0;l1<=3;l1++)for(int l2=0;l2<=3;l2++){
    int lo = l1>l2? l1-l2 : l2-l1;
    int hi = (l1+l2<3)? (l1+l2) : 3;
    for(int L=lo;L<=hi;L++){
      int n=(2*l1+1)*(2*l2+1)*(2*L+1);
      for(int i=0;i<n;i++) v.push_back((float)(r.gauss()*0.2));
    }
  }
  return v;
}

// ---------------- small setup kernels ----------------
__global__ __launch_bounds__(256) void k_cemb(const float* __restrict__ emb_table,
    const int* __restrict__ species, float* __restrict__ cemb, int* __restrict__ counts, int N){
  int i = blockIdx.x*256 + threadIdx.x;
  if(i < N) counts[i] = 0;
  if(i < N*32){ int n = i>>5, c = i&31; cemb[i] = emb_table[species[n]*32 + c]; }
}

__global__ __launch_bounds__(256) void k_hist(const int* __restrict__ centers, int* counts, int P){
  int i = blockIdx.x*256 + threadIdx.x;
  if(i < P) atomicAdd(&counts[centers[i]], 1);
}

__global__ __launch_bounds__(256) void k_scan(const int* __restrict__ counts,
    int* __restrict__ offsets, int* __restrict__ cursor, int N){
  __shared__ int part[256];
  const int t = threadIdx.x;
  const int CH = (N + 255)/256;
  const int lo = t*CH;
  int hi = (t+1)*CH; if(hi > N) hi = N;
  int s = 0;
  for(int i=lo;i<hi;i++) s += counts[i];
  part[t] = s; __syncthreads();
  const int own = s;
  for(int d=1; d<256; d<<=1){
    int v = (t>=d)? part[t-d] : 0;
    __syncthreads();
    part[t] += v;
    __syncthreads();
  }
  int run = part[t] - own;
  for(int i=lo;i<hi;i++){ offsets[i]=run; cursor[i]=run; run += counts[i]; }
  if(t==255) offsets[N] = part[255];
}

__global__ __launch_bounds__(256) void k_scatter(const int* __restrict__ centers,
    int* cursor, int* __restrict__ perm, int P){
  int i = blockIdx.x*256 + threadIdx.x;
  if(i < P){ int c = centers[i]; int pos = atomicAdd(&cursor[c], 1); perm[pos] = i; }
}

// ---------------- pair-order precompute: edge components + neighbor ids ----------------
__global__ __launch_bounds__(256) void k_permute(const float* __restrict__ sh,
    const float* __restrict__ rb, const int* __restrict__ nbrs, const int* __restrict__ perm,
    float* __restrict__ edge_p, int* __restrict__ nbrp, int P){
  int u = blockIdx.x*256 + threadIdx.x;
  int pos = u>>4, i = u&15;
  if(pos >= P) return;
  int p = perm[pos];
  if(i==0) nbrp[pos] = nbrs[p];
  int l = (i==0)?0:(i<4)?1:(i<9)?2:3;
  float s=0.f;
  for(int n=RBBc[l]; n<RBBc[l+1]; n++) s += rb[p*20+n];
  edge_p[(size_t)pos*16+i] = sh[p*16+i]*0.1f*s;   // sh * NU_SCALING * rb.sum
}

// ---------------- grouped fp16 gather table, neighbor-embedding BAKED IN ------------
// featsAg[n][g][r][i] (stride GSTR dwords = 4096 B/atom) = fp16(featsA[n][roff(g,r)+i] * cemb[n][i&31])
__global__ __launch_bounds__(256) void k_halfg(const float* __restrict__ src,
    const float* __restrict__ cemb, unsigned int* __restrict__ dst, int N){
  int u = blockIdx.x*256 + threadIdx.x;
  if(u >= N*GSTR) return;
  int n = u >> 10, o = u & 1023;          // o: dword within atom record
  int g = o >> 6, i = o & 63;             // g: wave group, i: lane
  float c = cemb[n*32 + (i&31)];
  float v0 = src[(size_t)n*FTOT + RFA.r0[g] + i] * c;
  float v1 = src[(size_t)n*FTOT + RFA.r1[g] + i] * c;
  _Float16 h0 = (_Float16)v0, h1 = (_Float16)v1;
  unsigned int lo = *(unsigned short*)&h0, hi = *(unsigned short*)&h1;
  dst[u] = lo | (hi<<16);
}

// ---------------- invariant MP (batched pairs, 3 barriers / 8 pairs) ----------------
__global__ __launch_bounds__(256) void k_inv(const float* __restrict__ sh, const float* __restrict__ rb,
    const float* __restrict__ cemb, const int* __restrict__ nbrs, const int* __restrict__ offsets,
    const int* __restrict__ perm, float* __restrict__ feats){
  const int a = blockIdx.x, t = threadIdx.x;
  __shared__ float sh_s[8][16], rb_s[8][20], emb_s[8][32], shrb_s[8][60];
  const int c = t & 31, rg = t >> 5;
  float acc[8];
  #pragma unroll
  for(int j=0;j<8;j++) acc[j] = 0.f;
  const int beg = offsets[a], cnt = offsets[a+1]-beg;
  for(int jb=0; jb<cnt; jb+=8){
    __syncthreads();
    for(int u=t; u<8*36; u+=256){
      int j=u/36, i=u-36*j;
      if(jb+j<cnt){
        int p=perm[beg+jb+j];
        if(i<16) sh_s[j][i]=sh[p*16+i]*0.1f;      // NU_SCALING
        else     rb_s[j][i-16]=rb[p*20+i-16];
      }
    }
    for(int u=t; u<8*32; u+=256){
      int j=u>>5, i=u&31;
      if(jb+j<cnt){ int nb=nbrs[perm[beg+jb+j]]; emb_s[j][i]=cemb[(size_t)nb*32+i]; }
    }
    __syncthreads();
    for(int u=t; u<8*60; u+=256){
      int j=u/60, r=u-60*j;
      if(jb+j<cnt) shrb_s[j][r] = sh_s[j][RWS.sh[r]] * rb_s[j][RWS.rb[r]];
    }
    __syncthreads();
    const int jm = (cnt-jb<8)?(cnt-jb):8;
    for(int j=0;j<jm;j++){
      const float e = emb_s[j][c];
      #pragma unroll
      for(int q=0;q<8;q++){ int r=rg+8*q; if(r<60) acc[q]=fmaf(shrb_s[j][r], e, acc[q]); }
    }
  }
  #pragma unroll
  for(int q=0;q<8;q++){
    int r = rg + 8*q;
    if(r < 60) feats[(size_t)a*FTOT + RWS.off[r] + c] = 0.1f * acc[q];  // MP_SCALING
  }
}

// ---------------- CG iterate (in-place): feats = feats + 0.1 * TP(feats, feats) ----------------
__device__ __forceinline__ float cg_u(const float* __restrict__ cg, int idx){
  return cg[__builtin_amdgcn_readfirstlane(idx)];
}
__global__ __launch_bounds__(256) void k_tp(float* __restrict__ feats, const float* __restrict__ cg){
  const int a = blockIdx.x, t = threadIdx.x;
  __shared__ float f_s[FTOT];
  float* fa = feats + (size_t)a*FTOT;
  for(int i=t;i<FTOT;i+=256)  f_s[i]  = fa[i];
  __syncthreads();
  #pragma unroll
  for(int L=0; L<4; L++){
    const int KLL = KLc[L], nL = 2*L+1;
    const int nel = nL*KLL;
    for(int e=t; e<nel; e+=256){
      const int M = e / KLL, k = e - M*KLL;
      float acc = 0.f;
      #pragma unroll
      for(int gi=0; gi<LG.cnt[L]; gi++){
        const int ci = LG.list[L][gi];
        const int l1 = CB.l1[ci], l2 = CB.l2[ci];
        if(k < CB.kk[ci]){
          const int n2 = 2*l2+1;
          #pragma unroll
          for(int aa=0; aa<2*l1+1; aa++){
            const float Av = f_s[FBc[l1] + aa*KLc[l1] + k];
            #pragma unroll
            for(int b=0; b<n2; b++)
              acc += cg_u(cg, CB.cgoff[ci] + (aa*n2+b)*nL + M) * (Av * f_s[FBc[l2] + b*KLc[l2] + k]);
          }
        }
      }
      fa[FBc[L] + M*KLL + k] = f_s[FBc[L] + M*KLL + k] + 0.1f*acc;   // NU_SCALING residual
    }
  }
}

// ---------------- equivariant MP v15: r7 base + dwordx16 edges + 2-pair-batched waits ----------------
template<int G,int PH,int U>
__device__ __forceinline__ void contract_combos(const float* __restrict__ stageT,
    float* __restrict__ out_s, const float* __restrict__ cg, int lane){
  if constexpr (U < CA.cnt[G]) {
    constexpr int ci = CA.ci[G][U];
    if constexpr (combo_in_phase(ci,PH)) {
      constexpr int l1=CB.l1[ci], l2=CB.l2[ci], L=CB.L[ci];
      constexpr int n1=2*l1+1, n2=2*l2+1, nL=2*L+1;
      constexpr int kt=phase_kt(PH);
      constexpr int rbase = rb_base(kt,l1,l2) - phase_rbadj(PH);
      float oa[nL];
      #pragma unroll
      for(int M=0;M<nL;M++) oa[M]=0.f;
      #pragma unroll
      for(int aa=0;aa<n1;aa++){
        #pragma unroll
        for(int b=0;b<n2;b++){
          const float sv = stageT[lane*RPAD + rbase + aa*n2 + b];
          #pragma unroll
          for(int M=0;M<nL;M++)
            oa[M] = fmaf(cg[CB.cgoff[ci] + (aa*n2+b)*nL + M], sv, oa[M]);  // uniform idx -> s_load
        }
      }
      #pragma unroll
      for(int M=0;M<nL;M++)
        atomicAdd(&out_s[FBc[L] + M*KLc[L] + kt*64 + lane], oa[M]);
    }
    contract_combos<G,PH,U+1>(stageT,out_s,cg,lane);
  }
}

template<int G,int PH>
__device__ __forceinline__ void eq_phase(const float* acc, float* stageT, float* out_s,
    const float* __restrict__ cg, int lane){
  __syncthreads();                       // protect previous phase's stage reads
  #pragma unroll
  for(int s=0;s<32;s++){
    if(ET.sph[G][s]==PH) stageT[lane*RPAD + ET.srow[G][s]] = acc[s];  // constexpr-folded
  }
  __syncthreads();
  contract_combos<G,PH,0>(stageT,out_s,cg,lane);
}

template<int G>
__device__ __forceinline__ void eq_phases(const float* acc, float* stageT, float* out_s,
    const float* __restrict__ cg, int lane){
  eq_phase<G,0>(acc,stageT,out_s,cg,lane);
  eq_phase<G,1>(acc,stageT,out_s,cg,lane);
  eq_phase<G,2>(acc,stageT,out_s,cg,lane);
  eq_phase<G,3>(acc,stageT,out_s,cg,lane);
  eq_phase<G,4>(acc,stageT,out_s,cg,lane);
}

typedef float sf16 __attribute__((ext_vector_type(16)));

__global__ __launch_bounds__(1024,8) void k_eq2(const float* __restrict__ edge_p,
    const int* __restrict__ nbrp, const int* __restrict__ offsets,
    const unsigned int* __restrict__ featsAg,
    float* __restrict__ featsB, const float* __restrict__ cg){
  __shared__ float stageT[64*RPAD];   // 38144 B, odd lane stride -> conflict-free
  __shared__ float out_s[FTOT];       // 7680 B
  const int a = blockIdx.x, t = threadIdx.x, lane = t&63, g = t>>6;

  float acc[32];
  #pragma unroll
  for(int s=0;s<32;s++) acc[s]=0.f;
  for(int i=t;i<FTOT;i+=1024) out_s[i]=0.f;
  const int beg = __builtin_amdgcn_readfirstlane(offsets[a]);
  const int cnt = __builtin_amdgcn_readfirstlane(offsets[a+1]) - beg;

  if(cnt > 0){
    // DEPTH rotating prefetch slots for the gathered fg dword (vmcnt-pipelined)
    unsigned int fgS[DEPTH];
    #pragma unroll
    for(int s=0;s<DEPTH;s++){
      int idx = (s < cnt) ? s : cnt-1;
      int nb = __builtin_amdgcn_readfirstlane(nbrp[beg+idx]);
      fgS[s] = featsAg[(size_t)(unsigned)nb*GSTR + t];
    }
    for(int j=0;j<cnt;j+=DEPTH){
      #pragma unroll
      for(int s=0;s<DEPTH;s+=2){
        const int q0 = j+s, q1 = j+s+1;
        if(q0 < cnt){
          // batched wave-uniform scalar loads: 2 pairs' edges (2 x 64B, 64B-aligned)
          // + 2 refill nb's (DEPTH ahead). ONE lgkmcnt drain per 2 pairs.
          sf16 eA, eB; int nb0, nb1;
          const float* ep0 = edge_p + (size_t)(beg+q0)*16;
          const float* ep1 = edge_p + (size_t)(beg+((q1<cnt)?q1:q0))*16;
          int qa = q0 + DEPTH; if(qa >= cnt) qa = cnt-1;
          int qb = q1 + DEPTH; if(qb >= cnt) qb = cnt-1;
          const int* npa = nbrp + beg + qa;
          const int* npb = nbrp + beg + qb;
          asm volatile("s_load_dwordx16 %0, %2, 0\n\t"
                       "s_load_dwordx16 %1, %3, 0"
                       : "=s"(eA), "=s"(eB) : "s"(ep0), "s"(ep1));
          asm volatile("s_load_dword %0, %2, 0\n\t"
                       "s_load_dword %1, %3, 0"
                       : "=s"(nb0), "=s"(nb1) : "s"(npa), "s"(npb));
          asm volatile("s_waitcnt lgkmcnt(0)"
                       : "+s"(eA), "+s"(eB), "+s"(nb0), "+s"(nb1));
          __builtin_amdgcn_sched_barrier(0);
          // ---- pair q0 ----
          {
            const unsigned int v = fgS[s];               // vmcnt wait (compiler)
            fgS[s] = featsAg[(size_t)(unsigned)nb0*GSTR + t];
            union { unsigned int u; _Float16 h[2]; } cv; cv.u = v;
            const float f0 = (float)cv.h[0], f1 = (float)cv.h[1];
            #pragma unroll
            for(int i=0;i<16;i++){
              acc[i]    = fmaf(eA[i], f0, acc[i]);
              acc[16+i] = fmaf(eA[i], f1, acc[16+i]);
            }
          }
          // ---- pair q1 ----
          if(q1 < cnt){
            const unsigned int v = fgS[s+1];
            fgS[s+1] = featsAg[(size_t)(unsigned)nb1*GSTR + t];
            union { unsigned int u; _Float16 h[2]; } cv; cv.u = v;
            const float f0 = (float)cv.h[0], f1 = (float)cv.h[1];
            #pragma unroll
            for(int i=0;i<16;i++){
              acc[i]    = fmaf(eB[i], f0, acc[i]);
              acc[16+i] = fmaf(eB[i], f1, acc[16+i]);
            }
          }
        }
      }
    }
  }

  // once-per-block contract phases (each begins with __syncthreads -> covers out_s init)
  switch(g){
    case 0:  eq_phases<0 >(acc,stageT,out_s,cg,lane); break;
    case 1:  eq_phases<1 >(acc,stageT,out_s,cg,lane); break;
    case 2:  eq_phases<2 >(acc,stageT,out_s,cg,lane); break;
    case 3:  eq_phases<3 >(acc,stageT,out_s,cg,lane); break;
    case 4:  eq_phases<4 >(acc,stageT,out_s,cg,lane); break;
    case 5:  eq_phases<5 >(acc,stageT,out_s,cg,lane); break;
    case 6:  eq_phases<6 >(acc,stageT,out_s,cg,lane); break;
    case 7:  eq_phases<7 >(acc,stageT,out_s,cg,lane); break;
    case 8:  eq_phases<8 >(acc,stageT,out_s,cg,lane); break;
    case 9:  eq_phases<9 >(acc,stageT,out_s,cg,lane); break;
    case 10: eq_phases<10>(acc,stageT,out_s,cg,lane); break;
    case 11: eq_phases<11>(acc,stageT,out_s,cg,lane); break;
    case 12: eq_phases<12>(acc,stageT,out_s,cg,lane); break;
    case 13: eq_phases<13>(acc,stageT,out_s,cg,lane); break;
    case 14: eq_phases<14>(acc,stageT,out_s,cg,lane); break;
    default: eq_phases<15>(acc,stageT,out_s,cg,lane); break;
  }
  __syncthreads();
  float* ob = featsB + (size_t)a*FTOT;
  for(int i=t;i<FTOT;i+=1024) ob[i] = 0.1f*out_s[i];       // MP_SCALING
}

// ---------------- energy readout ----------------
__global__ __launch_bounds__(256) void k_energy(const float* __restrict__ feats,
    const float* __restrict__ cemb, const float* __restrict__ wE, const float* __restrict__ bE,
    float* __restrict__ out, int N){
  const int wid = threadIdx.x >> 6, lane = threadIdx.x & 63;
  const int a = blockIdx.x*4 + wid;
  if(a >= N) return;
  const float e = cemb[(size_t)a*32 + (lane & 31)];
  float s = 0.f;
  for(int k=lane; k<256; k+=64) s += feats[(size_t)a*FTOT + k] * e * wE[k];
  #pragma unroll
  for(int off=32; off; off>>=1) s += __shfl_down(s, off, 64);
  if(lane == 0) out[a] = s + bE[0];
}

// ---------------- launcher ----------------
extern "C" void kernel_launch(void* const* d_in, const int* in_sizes, int n_in,
                              void* d_out, int out_size, void* d_ws, size_t ws_size,
                              hipStream_t stream){
  const float* sh        = (const float*)d_in[0];
  const float* rb        = (const float*)d_in[1];
  const float* emb_table = (const float*)d_in[2];
  const float* wE        = (const float*)d_in[3];
  const float* bE        = (const float*)d_in[4];
  const int*   species   = (const int*)d_in[5];
  const int*   centers   = (const int*)d_in[6];
  const int*   nbrs      = (const int*)d_in[7];
  const int N = in_sizes[5];
  const int P = in_sizes[6];

  char* ws = (char*)d_ws; size_t off = 0;
  auto carve = [&](size_t bytes)->void*{
    void* p = ws + off; off = (off + bytes + 255) & ~(size_t)255; return p;
  };
  float* cg_d    = (float*)carve((size_t)CGTOT*4);
  float* cemb    = (float*)carve((size_t)N*32*4);
  int*   counts  = (int*)  carve((size_t)N*4);
  int*   offsets = (int*)  carve((size_t)(N+1)*4);
  int*   cursor  = (int*)  carve((size_t)N*4);
  int*   perm    = (int*)  carve((size_t)P*4);
  float* edge_pd = (float*)carve((size_t)(P+4)*16*4);
  int*   nbrp    = (int*)  carve((size_t)(P+DEPTH+2)*4);
  float* featsA  = (float*)carve((size_t)N*FTOT*4);
  float* featsB  = (float*)carve((size_t)N*FTOT*4);
  unsigned int* featsAg = (unsigned int*)carve((size_t)N*GSTR*4);
  (void)ws_size; (void)n_in; (void)out_size;

  static const std::vector<float> cg_host = build_cg();  // deterministic; host-side cache only
  hipMemcpyAsync(cg_d, cg_host.data(), (size_t)CGTOT*4, hipMemcpyHostToDevice, stream);

  k_cemb   <<<(N*32 + 255)/256, 256, 0, stream>>>(emb_table, species, cemb, counts, N);
  k_hist   <<<(P + 255)/256,    256, 0, stream>>>(centers, counts, P);
  k_scan   <<<1,                256, 0, stream>>>(counts, offsets, cursor, N);
  k_scatter<<<(P + 255)/256,    256, 0, stream>>>(centers, cursor, perm, P);
  k_permute<<<(P*16 + 255)/256, 256, 0, stream>>>(sh, rb, nbrs, perm, edge_pd, nbrp, P);
  k_inv    <<<N,                256, 0, stream>>>(sh, rb, cemb, nbrs, offsets, perm, featsA);
  k_tp     <<<N,                256, 0, stream>>>(featsA, cg_d);
  k_halfg  <<<(N*GSTR + 255)/256, 256, 0, stream>>>(featsA, cemb, featsAg, N);
  k_eq2    <<<N,               1024, 0, stream>>>(edge_pd, nbrp, offsets, featsAg, featsB, cg_d);
  k_tp     <<<N,                256, 0, stream>>>(featsB, cg_d);
  k_energy <<<(N + 3)/4,        256, 0, stream>>>(featsB, cemb, wE, bE, (float*)d_out, N);
}